// Round 1
// baseline (1794.887 us; speedup 1.0000x reference)
//
#include <hip/hip_runtime.h>
#include <hip/hip_bf16.h>
#include <cstdint>

#define BB 8
#define NV 1024
#define HH 128
#define DH 32
#define NCOE 50
#define NSC 4

typedef __attribute__((ext_vector_type(8))) short short8;
typedef __attribute__((ext_vector_type(4))) float f32x4;

__device__ __forceinline__ ushort f2bf(float f) {
    uint32_t x = __float_as_uint(f);
    uint32_t r = x + 0x7FFFu + ((x >> 16) & 1u);
    return (ushort)(r >> 16);
}

// ---------------- K1: sine encoding + eigw linear -> eig [B*N,128] ----------------
__global__ void k_sine_linear(const float* __restrict__ ev, const float* __restrict__ W,
                              const float* __restrict__ bias, float* __restrict__ eig) {
    __shared__ float ee[HH + 1];
    int row = blockIdx.x;   // b*N + n
    int t = threadIdx.x;    // 0..127
    float e = ev[row];
    if (t < 64) {
        float div = expf((float)(2 * t) * -0.07195578415606394f); // -ln(10000)/128
        float pe = e * 100.0f * div;
        ee[1 + t] = sinf(pe);
        ee[65 + t] = cosf(pe);
    }
    if (t == 0) ee[0] = e;
    __syncthreads();
    const float* wr = W + t * (HH + 1);
    float acc = bias[t];
    for (int j = 0; j < HH + 1; ++j) acc += ee[j] * wr[j];
    eig[(size_t)row * HH + t] = acc;
}

// ---------------- block reduction helper (128 threads = 2 waves) ----------------
__device__ __forceinline__ float block_sum_128(float v, float* tmp, int t) {
#pragma unroll
    for (int off = 32; off; off >>= 1) v += __shfl_xor(v, off);
    if ((t & 63) == 0) tmp[t >> 6] = v;
    __syncthreads();
    float r = tmp[0] + tmp[1];
    __syncthreads();
    return r;
}

// ---------------- K2: LN1 + QKV ----------------
__global__ void k_ln_qkv(const float* __restrict__ eig, const float* __restrict__ g,
                         const float* __restrict__ be, const float* __restrict__ W,
                         const float* __restrict__ bias, float* __restrict__ qkv) {
    __shared__ float x[HH];
    __shared__ float tmp[2];
    int row = blockIdx.x, t = threadIdx.x;
    float e = eig[(size_t)row * HH + t];
    float mean = block_sum_128(e, tmp, t) * (1.0f / HH);
    float d = e - mean;
    float var = block_sum_128(d * d, tmp, t) * (1.0f / HH);
    x[t] = d * rsqrtf(var + 1e-5f) * g[t] + be[t];
    __syncthreads();
#pragma unroll
    for (int c = 0; c < 3; ++c) {
        int o = c * HH + t;
        const float* wr = W + (size_t)o * HH;
        float acc = bias[o];
        for (int j = 0; j < HH; ++j) acc += x[j] * wr[j];
        qkv[(size_t)row * 384 + o] = acc;
    }
}

// ---------------- K3: attention (one wave per query row, online softmax) ----------------
__global__ __launch_bounds__(256) void k_attn(const float* __restrict__ qkv, float* __restrict__ o) {
    __shared__ float qs[4][DH];
    int bid = blockIdx.x;
    int bh = bid >> 8;          // 0..31
    int rowblk = bid & 255;
    int b = bh >> 2, h = bh & 3;
    int t = threadIdx.x, w = t >> 6, lane = t & 63;
    int row = rowblk * 4 + w;
    const float* qr = qkv + ((size_t)(b * NV + row) * 384) + h * DH;
    if (lane < DH) qs[w][lane] = qr[lane];
    __syncthreads();
    const float* kbase = qkv + (size_t)b * NV * 384 + 128 + h * DH;
    const float* vbase = qkv + (size_t)b * NV * 384 + 256 + h * DH;
    float m = -INFINITY, l = 0.f;
    float acc[DH];
#pragma unroll
    for (int d = 0; d < DH; ++d) acc[d] = 0.f;
    for (int it = 0; it < NV / 64; ++it) {
        int key = it * 64 + lane;
        const float* kr = kbase + (size_t)key * 384;
        float s = 0.f;
#pragma unroll
        for (int d4 = 0; d4 < DH / 4; ++d4) {
            float4 kv = *(const float4*)(kr + d4 * 4);
            s += qs[w][d4 * 4 + 0] * kv.x + qs[w][d4 * 4 + 1] * kv.y +
                 qs[w][d4 * 4 + 2] * kv.z + qs[w][d4 * 4 + 3] * kv.w;
        }
        s *= 0.17677669529663687f;  // 1/sqrt(32)
        float mn = fmaxf(m, s);
        float corr = __expf(m - mn);   // exp(-inf)=0 on first iter
        float p = __expf(s - mn);
        l = l * corr + p;
        const float* vr = vbase + (size_t)key * 384;
#pragma unroll
        for (int d4 = 0; d4 < DH / 4; ++d4) {
            float4 vv = *(const float4*)(vr + d4 * 4);
            acc[d4 * 4 + 0] = acc[d4 * 4 + 0] * corr + p * vv.x;
            acc[d4 * 4 + 1] = acc[d4 * 4 + 1] * corr + p * vv.y;
            acc[d4 * 4 + 2] = acc[d4 * 4 + 2] * corr + p * vv.z;
            acc[d4 * 4 + 3] = acc[d4 * 4 + 3] * corr + p * vv.w;
        }
        m = mn;
    }
    float mA = m;
#pragma unroll
    for (int off = 32; off; off >>= 1) mA = fmaxf(mA, __shfl_xor(mA, off));
    float c = __expf(m - mA);
    float lc = l * c;
#pragma unroll
    for (int off = 32; off; off >>= 1) lc += __shfl_xor(lc, off);
    float inv = 1.f / lc;
    float myo = 0.f;
#pragma unroll
    for (int d = 0; d < DH; ++d) {
        float v = acc[d] * c;
#pragma unroll
        for (int off = 32; off; off >>= 1) v += __shfl_xor(v, off);
        if (lane == d) myo = v;
    }
    if (lane < DH) o[(size_t)(b * NV + row) * HH + h * DH + lane] = myo * inv;
}

// ---------------- K4: output projection + residual ----------------
__global__ void k_proj(const float* __restrict__ o, const float* __restrict__ W,
                       const float* __restrict__ bias, float* __restrict__ eig) {
    __shared__ float xr[HH];
    int row = blockIdx.x, t = threadIdx.x;
    xr[t] = o[(size_t)row * HH + t];
    __syncthreads();
    const float* wr = W + (size_t)t * HH;
    float acc = bias[t];
    for (int j = 0; j < HH; ++j) acc += xr[j] * wr[j];
    eig[(size_t)row * HH + t] += acc;
}

// ---------------- K5: LN2 + FFN + residual ----------------
__global__ void k_ffn(float* __restrict__ eig, const float* __restrict__ g2, const float* __restrict__ bv,
                      const float* __restrict__ W1, const float* __restrict__ b1,
                      const float* __restrict__ W2, const float* __restrict__ b2) {
    __shared__ float x[HH];
    __shared__ float hbuf[HH];
    __shared__ float tmp[2];
    int row = blockIdx.x, t = threadIdx.x;
    float e = eig[(size_t)row * HH + t];
    float mean = block_sum_128(e, tmp, t) * (1.0f / HH);
    float d = e - mean;
    float var = block_sum_128(d * d, tmp, t) * (1.0f / HH);
    x[t] = d * rsqrtf(var + 1e-5f) * g2[t] + bv[t];
    __syncthreads();
    const float* w1 = W1 + (size_t)t * HH;
    float a = b1[t];
    for (int j = 0; j < HH; ++j) a += x[j] * w1[j];
    float ge = 0.5f * a * (1.0f + erff(a * 0.7071067811865475f));  // exact gelu
    hbuf[t] = ge;
    __syncthreads();
    const float* w2 = W2 + (size_t)t * HH;
    float y = b2[t];
    for (int j = 0; j < HH; ++j) y += hbuf[j] * w2[j];
    eig[(size_t)row * HH + t] = e + y;
}

// ---------------- K6: mean pool over N ----------------
__global__ void k_meanpool(const float* __restrict__ eig, float* __restrict__ me) {
    int b = blockIdx.x, t = threadIdx.x;
    float s = 0.f;
    const float* p = eig + (size_t)b * NV * HH + t;
    for (int n = 0; n < NV; ++n) s += p[(size_t)n * HH];
    me[b * HH + t] = s * (1.0f / NV);
}

// ---------------- K7: decoders (sigmoid + normalize) ----------------
__global__ void k_decoders(const float* __restrict__ me,
                           const float* __restrict__ dscW, const float* __restrict__ dscb,
                           const float* __restrict__ dwavW, const float* __restrict__ dwavb,
                           const float* __restrict__ dsclW, const float* __restrict__ dsclb,
                           float* __restrict__ cs, float* __restrict__ cw, float* __restrict__ csc) {
    __shared__ float m[HH];
    __shared__ float s1[NCOE], s2[NCOE];
    __shared__ float sums[2];
    int b = blockIdx.x, t = threadIdx.x;  // 64 threads
    m[t] = me[b * HH + t];
    m[t + 64] = me[b * HH + t + 64];
    __syncthreads();
    if (t < NCOE) {
        float a = dscb[t], a2 = dwavb[t];
        const float* w1 = dscW + t * HH;
        const float* w2 = dwavW + t * HH;
        for (int j = 0; j < HH; ++j) { a += m[j] * w1[j]; a2 += m[j] * w2[j]; }
        s1[t] = 1.f / (1.f + __expf(-a));
        s2[t] = 1.f / (1.f + __expf(-a2));
    }
    if (t < NSC) {
        float a = dsclb[t];
        const float* wv = dsclW + t * HH;
        for (int j = 0; j < HH; ++j) a += m[j] * wv[j];
        csc[b * NSC + t] = 5.0f / (1.f + __expf(-a));  // THRE * sigmoid
    }
    __syncthreads();
    if (t == 0) {
        float a = 0.f, bb = 0.f;
        for (int c = 0; c < NCOE; ++c) { a += s1[c]; bb += s2[c]; }
        sums[0] = a; sums[1] = bb;
    }
    __syncthreads();
    if (t < NCOE) {
        cs[b * NCOE + t] = s1[t] / (sums[0] + 1e-8f);
        cw[b * NCOE + t] = s2[t] / (sums[1] + 1e-8f);
    }
}

// ---------------- K8: Chebyshev recurrences -> fsaT [B,5,N] (normalized) ----------------
__global__ void k_fsa(const float* __restrict__ ev, const float* __restrict__ cs,
                      const float* __restrict__ cw, const float* __restrict__ csc,
                      float* __restrict__ fsaT) {
    __shared__ float lcs[NCOE], lcw[NCOE], lsc[NSC];
    int gid = blockIdx.x * 256 + threadIdx.x;
    int b = gid >> 10, n = gid & (NV - 1);
    int t = threadIdx.x;
    if (t < NCOE) { lcs[t] = cs[b * NCOE + t]; lcw[t] = cw[b * NCOE + t]; }
    if (t < NSC) lsc[t] = csc[b * NSC + t];
    __syncthreads();
    float e = ev[gid];
    // scaling: sum_c cs[c] * 0.5*(1 - T_{2c+1}(e-1))
    float x = e - 1.0f;
    float te = 1.f, to = x;
    float a0 = lcs[0] * 0.5f * (1.f - to);
    for (int c = 1; c < NCOE; ++c) {
        te = 2.f * x * to - te;
        to = 2.f * x * te - to;
        a0 += lcs[c] * 0.5f * (1.f - to);
    }
    // wavelets: sum_c cw[c] * 0.5*(1 - T_{2c}(y)),  y = (e*scale masked) - 1
    float aw[NSC];
#pragma unroll
    for (int s = 0; s < NSC; ++s) {
        float f = e * lsc[s];
        if (f > 2.0f) f = 0.0f;
        float y = f - 1.0f;
        float te2 = 1.f, to2 = y, a = 0.f;  // c=0 term: 0.5*(1-T0)=0
        for (int c = 1; c < NCOE; ++c) {
            te2 = 2.f * y * to2 - te2;
            to2 = 2.f * y * te2 - to2;
            a += lcw[c] * 0.5f * (1.f - te2);
        }
        aw[s] = a;
    }
    float n2 = a0 * a0;
#pragma unroll
    for (int s = 0; s < NSC; ++s) n2 += aw[s] * aw[s];
    float inv = 1.f / (sqrtf(n2) + 1e-8f);
    fsaT[((size_t)b * 5 + 0) * NV + n] = a0 * inv;
#pragma unroll
    for (int s = 0; s < NSC; ++s) fsaT[((size_t)b * 5 + 1 + s) * NV + n] = aw[s] * inv;
}

// ---------------- K9: eigenvector f32 -> bf16 ----------------
__global__ void k_tobf16(const float* __restrict__ in, ushort* __restrict__ outp) {
    int i = blockIdx.x * 256 + threadIdx.x;  // 1M threads x 8 elems
    const float4* p = (const float4*)in + (size_t)i * 2;
    float4 a = p[0], bq = p[1];
    uint4 r;
    r.x = (uint)f2bf(a.x) | ((uint)f2bf(a.y) << 16);
    r.y = (uint)f2bf(a.z) | ((uint)f2bf(a.w) << 16);
    r.z = (uint)f2bf(bq.x) | ((uint)f2bf(bq.y) << 16);
    r.w = (uint)f2bf(bq.z) | ((uint)f2bf(bq.w) << 16);
    ((uint4*)outp)[i] = r;
}

// ---------------- K10: batched GEMM  C[n,m] = sum_k (V[n,k]*fsa[k]) * V[m,k] ----------------
// m97 structure: 128x128 tile, BK=32, 4 waves x (4x4) mfma_f32_16x16x32_bf16,
// B operand via global_load_lds width 16, A operand register-staged with fsa scale.
__global__ __launch_bounds__(256) void k_gemm(const ushort* __restrict__ Vb,
                                              const float* __restrict__ fsaT,
                                              float* __restrict__ out,
                                              float* __restrict__ cn) {
    __shared__ ushort As[128 * 32];
    __shared__ ushort Bs[128 * 32];
    int tile = blockIdx.x;      // 0..63
    int bsid = blockIdx.y;      // 0..39
    int b = bsid / 5, s = bsid % 5;
    int n0 = (tile >> 3) * 128, m0 = (tile & 7) * 128;
    int tid = threadIdx.x, lane = tid & 63, w = tid >> 6;
    int wr = w >> 1, wc = w & 1;
    const ushort* Vbase = Vb + (size_t)b * NV * NV;
    const float* fs = fsaT + ((size_t)b * 5 + s) * NV;
    f32x4 acc[4][4] = {};

    for (int kt = 0; kt < NV / 32; ++kt) {
        int k0 = kt * 32;
        __syncthreads();
        // B tile: async direct-to-LDS, 8 chunks of 1KB (wave w -> chunks 2w, 2w+1)
#pragma unroll
        for (int p = 0; p < 2; ++p) {
            int ci = w * 2 + p;
            int rrow = ci * 16 + (lane >> 2);
            int kch = (lane & 3) * 8;
            const ushort* gp = Vbase + (size_t)(m0 + rrow) * NV + k0 + kch;
            __builtin_amdgcn_global_load_lds((const __attribute__((address_space(1))) void*)gp,
                                             (__attribute__((address_space(3))) void*)(Bs + ci * 512),
                                             16, 0, 0);
        }
        // A tile: register staged, scaled by fsa[k]
#pragma unroll
        for (int p = 0; p < 2; ++p) {
            int idx = p * 256 + tid;
            int rrow = idx >> 2;
            int kch = (idx & 3) * 8;
            const ushort* gp = Vbase + (size_t)(n0 + rrow) * NV + k0 + kch;
            uint4 raw = *(const uint4*)gp;
            const float4* fp = (const float4*)(fs + k0 + kch);
            float4 f0 = fp[0], f1 = fp[1];
            float v0 = __uint_as_float(raw.x << 16) * f0.x;
            float v1 = __uint_as_float(raw.x & 0xffff0000u) * f0.y;
            float v2 = __uint_as_float(raw.y << 16) * f0.z;
            float v3 = __uint_as_float(raw.y & 0xffff0000u) * f0.w;
            float v4 = __uint_as_float(raw.z << 16) * f1.x;
            float v5 = __uint_as_float(raw.z & 0xffff0000u) * f1.y;
            float v6 = __uint_as_float(raw.w << 16) * f1.z;
            float v7 = __uint_as_float(raw.w & 0xffff0000u) * f1.w;
            uint4 rr;
            rr.x = (uint)f2bf(v0) | ((uint)f2bf(v1) << 16);
            rr.y = (uint)f2bf(v2) | ((uint)f2bf(v3) << 16);
            rr.z = (uint)f2bf(v4) | ((uint)f2bf(v5) << 16);
            rr.w = (uint)f2bf(v6) | ((uint)f2bf(v7) << 16);
            *(uint4*)(As + rrow * 32 + kch) = rr;
        }
        __syncthreads();
        // compute
        int cl = lane & 15, q = lane >> 4;
        const ushort* ap = As + ((wr * 64 + cl) * 32 + q * 8);
        const ushort* bp = Bs + ((wc * 64 + cl) * 32 + q * 8);
        short8 af[4], bfr[4];
#pragma unroll
        for (int i = 0; i < 4; ++i) af[i] = *(const short8*)(ap + i * 512);
#pragma unroll
        for (int j = 0; j < 4; ++j) bfr[j] = *(const short8*)(bp + j * 512);
#pragma unroll
        for (int i = 0; i < 4; ++i)
#pragma unroll
            for (int j = 0; j < 4; ++j)
                acc[i][j] = __builtin_amdgcn_mfma_f32_16x16x32_bf16(af[i], bfr[j], acc[i][j], 0, 0, 0);
    }
    // epilogue: store raw filters + accumulate column sum-of-squares
    int cl = lane & 15, q = lane >> 4;
    size_t ob = (size_t)(s * BB + b) * NV * NV;
    float colss[4] = {0.f, 0.f, 0.f, 0.f};
#pragma unroll
    for (int i = 0; i < 4; ++i) {
        int rbase = n0 + wr * 64 + i * 16 + q * 4;
#pragma unroll
        for (int j = 0; j < 4; ++j) {
            int col = m0 + wc * 64 + j * 16 + cl;
#pragma unroll
            for (int r = 0; r < 4; ++r) {
                float v = acc[i][j][r];
                out[ob + (size_t)(rbase + r) * NV + col] = v;
                colss[j] += v * v;
            }
        }
    }
    float* cnb = cn + (size_t)(s * BB + b) * NV;
#pragma unroll
    for (int j = 0; j < 4; ++j) {
        float v = colss[j];
        v += __shfl_xor(v, 16);
        v += __shfl_xor(v, 32);
        if (q == 0) atomicAdd(cnb + (m0 + wc * 64 + j * 16 + cl), v);
    }
}

// ---------------- K11: in-place column normalization ----------------
__global__ void k_norm(float* __restrict__ out, const float* __restrict__ cn) {
    int bid = blockIdx.x;
    int bs = bid >> 10, n = bid & (NV - 1);
    int m4 = threadIdx.x * 4;
    float4 ssv = *(const float4*)(cn + (size_t)bs * NV + m4);
    float4* p = (float4*)(out + ((size_t)bs * NV + n) * NV + m4);
    float4 v = *p;
    v.x *= 1.f / fmaxf(sqrtf(ssv.x), 1e-12f);
    v.y *= 1.f / fmaxf(sqrtf(ssv.y), 1e-12f);
    v.z *= 1.f / fmaxf(sqrtf(ssv.z), 1e-12f);
    v.w *= 1.f / fmaxf(sqrtf(ssv.w), 1e-12f);
    *p = v;
}

extern "C" void kernel_launch(void* const* d_in, const int* in_sizes, int n_in,
                              void* d_out, int out_size, void* d_ws, size_t ws_size,
                              hipStream_t stream) {
    const float* eigenvalue = (const float*)d_in[0];
    const float* eigenvector = (const float*)d_in[1];
    const float* eigw_W = (const float*)d_in[2];
    const float* eigw_b = (const float*)d_in[3];
    const float* ln1_g = (const float*)d_in[4];
    const float* ln1_b = (const float*)d_in[5];
    const float* qkv_W = (const float*)d_in[6];
    const float* qkv_b = (const float*)d_in[7];
    const float* out_W = (const float*)d_in[8];
    const float* out_b = (const float*)d_in[9];
    const float* ln2_g = (const float*)d_in[10];
    const float* ln2_b = (const float*)d_in[11];
    const float* ffn1_W = (const float*)d_in[12];
    const float* ffn1_b = (const float*)d_in[13];
    const float* ffn2_W = (const float*)d_in[14];
    const float* ffn2_b = (const float*)d_in[15];
    const float* dsc_W = (const float*)d_in[16];
    const float* dsc_b = (const float*)d_in[17];
    const float* dwav_W = (const float*)d_in[18];
    const float* dwav_b = (const float*)d_in[19];
    const float* dscl_W = (const float*)d_in[20];
    const float* dscl_b = (const float*)d_in[21];
    // d_in[22] = length: always N (full graphs), mask is empty -> unused

    char* w = (char*)d_ws;
    float* eig  = (float*)(w + 0);            // 4,194,304
    float* qkv  = (float*)(w + 4194304);      // 12,582,912
    float* obuf = (float*)(w + 16777216);     // 4,194,304
    float* me   = (float*)(w + 20971520);     // 4,096
    float* cs   = (float*)(w + 20975616);     // 1,600 (pad 1792)
    float* cw   = (float*)(w + 20977408);     // 1,600 (pad 1792)
    float* csc  = (float*)(w + 20979200);     // 128 (pad 256)
    float* fsaT = (float*)(w + 20979456);     // 163,840
    float* cn   = (float*)(w + 21143296);     // 163,840
    ushort* Vb  = (ushort*)(w + 21307136);    // 16,777,216 -> total 38,084,352 B

    float* outp = (float*)d_out;

    hipMemsetAsync(cn, 0, 40 * NV * sizeof(float), stream);

    k_sine_linear<<<dim3(BB * NV), dim3(HH), 0, stream>>>(eigenvalue, eigw_W, eigw_b, eig);
    k_ln_qkv<<<dim3(BB * NV), dim3(HH), 0, stream>>>(eig, ln1_g, ln1_b, qkv_W, qkv_b, qkv);
    k_attn<<<dim3(BB * 4 * 256), dim3(256), 0, stream>>>(qkv, obuf);
    k_proj<<<dim3(BB * NV), dim3(HH), 0, stream>>>(obuf, out_W, out_b, eig);
    k_ffn<<<dim3(BB * NV), dim3(HH), 0, stream>>>(eig, ln2_g, ln2_b, ffn1_W, ffn1_b, ffn2_W, ffn2_b);
    k_meanpool<<<dim3(BB), dim3(HH), 0, stream>>>(eig, me);
    k_decoders<<<dim3(BB), dim3(64), 0, stream>>>(me, dsc_W, dsc_b, dwav_W, dwav_b, dscl_W, dscl_b, cs, cw, csc);
    k_fsa<<<dim3(BB * NV / 256), dim3(256), 0, stream>>>(eigenvalue, cs, cw, csc, fsaT);
    k_tobf16<<<dim3(BB * NV * NV / (8 * 256)), dim3(256), 0, stream>>>(eigenvector, Vb);
    k_gemm<<<dim3(64, 40), dim3(256), 0, stream>>>(Vb, fsaT, outp, cn);
    k_norm<<<dim3(40 * NV), dim3(256), 0, stream>>>(outp, cn);
}

// Round 2
// 942.242 us; speedup vs baseline: 1.9049x; 1.9049x over previous
//
#include <hip/hip_runtime.h>
#include <hip/hip_bf16.h>
#include <cstdint>

#define BB 8
#define NV 1024
#define HH 128
#define DH 32
#define NCOE 50
#define NSC 4

typedef __attribute__((ext_vector_type(8))) short short8;
typedef __attribute__((ext_vector_type(4))) float f32x4;

__device__ __forceinline__ ushort f2bf(float f) {
    uint32_t x = __float_as_uint(f);
    uint32_t r = x + 0x7FFFu + ((x >> 16) & 1u);
    return (ushort)(r >> 16);
}

// ---------------- K1: sine encoding + eigw linear -> eig [B*N,128] ----------------
__global__ void k_sine_linear(const float* __restrict__ ev, const float* __restrict__ W,
                              const float* __restrict__ bias, float* __restrict__ eig) {
    __shared__ float ee[HH + 1];
    int row = blockIdx.x;   // b*N + n
    int t = threadIdx.x;    // 0..127
    float e = ev[row];
    if (t < 64) {
        float div = expf((float)(2 * t) * -0.07195578415606394f); // -ln(10000)/128
        float pe = e * 100.0f * div;
        ee[1 + t] = sinf(pe);
        ee[65 + t] = cosf(pe);
    }
    if (t == 0) ee[0] = e;
    __syncthreads();
    const float* wr = W + t * (HH + 1);
    float acc = bias[t];
    for (int j = 0; j < HH + 1; ++j) acc += ee[j] * wr[j];
    eig[(size_t)row * HH + t] = acc;
}

// ---------------- block reduction helper (128 threads = 2 waves) ----------------
__device__ __forceinline__ float block_sum_128(float v, float* tmp, int t) {
#pragma unroll
    for (int off = 32; off; off >>= 1) v += __shfl_xor(v, off);
    if ((t & 63) == 0) tmp[t >> 6] = v;
    __syncthreads();
    float r = tmp[0] + tmp[1];
    __syncthreads();
    return r;
}

// ---------------- K2: LN1 + QKV -> bf16 head-major [bh][n][32] ----------------
__global__ void k_ln_qkv(const float* __restrict__ eig, const float* __restrict__ g,
                         const float* __restrict__ be, const float* __restrict__ W,
                         const float* __restrict__ bias,
                         ushort* __restrict__ qb, ushort* __restrict__ kb, ushort* __restrict__ vb) {
    __shared__ float x[HH];
    __shared__ float tmp[2];
    int row = blockIdx.x, t = threadIdx.x;
    int b = row >> 10, n = row & (NV - 1);
    float e = eig[(size_t)row * HH + t];
    float mean = block_sum_128(e, tmp, t) * (1.0f / HH);
    float d = e - mean;
    float var = block_sum_128(d * d, tmp, t) * (1.0f / HH);
    x[t] = d * rsqrtf(var + 1e-5f) * g[t] + be[t];
    __syncthreads();
    int h = t >> 5, dd = t & 31;
    size_t hidx = ((size_t)((b * 4 + h) * NV) + n) * DH + dd;
    ushort* dst[3] = {qb, kb, vb};
#pragma unroll
    for (int c = 0; c < 3; ++c) {
        int o = c * HH + t;
        const float* wr = W + (size_t)o * HH;
        float acc = bias[o];
        for (int j = 0; j < HH; ++j) acc += x[j] * wr[j];
        dst[c][hidx] = f2bf(acc);
    }
}

// ---------------- K3: V transpose -> vt [bh][32][1024] bf16 ----------------
__global__ __launch_bounds__(256) void k_vt(const ushort* __restrict__ vb, ushort* __restrict__ vt) {
    __shared__ ushort Ld[256 * 40];
    int bh = blockIdx.y, n0 = blockIdx.x * 256;
    int t = threadIdx.x;
    const ushort* src = vb + ((size_t)bh * NV + n0) * DH;
#pragma unroll
    for (int p = 0; p < 4; ++p) {
        int idx = p * 256 + t;         // 1024 chunk-slots of 8 ushorts
        int rowi = idx >> 2, ch = idx & 3;
        short8 u = *(const short8*)(src + idx * 8);
        *(short8*)(&Ld[rowi * 40 + ch * 8]) = u;
    }
    __syncthreads();
    int d = t >> 3, nc = (t & 7) * 32;
    ushort* dst = vt + ((size_t)bh * DH + d) * NV + n0 + nc;
#pragma unroll
    for (int p = 0; p < 4; ++p) {
        short8 u;
#pragma unroll
        for (int i = 0; i < 8; ++i) u[i] = (short)Ld[(nc + p * 8 + i) * 40 + d];
        *(short8*)(dst + p * 8) = u;
    }
}

// ---------------- K4: S = Q K^T / sqrt(dh), per (b,h). S f32 in d_out scratch ----------------
__global__ __launch_bounds__(256) void k_qk(const ushort* __restrict__ qb, const ushort* __restrict__ kb,
                                            float* __restrict__ S) {
    __shared__ ushort As[128 * 32];
    __shared__ ushort Bs[128 * 32];
    int tile = blockIdx.x;      // 0..63
    int bh = blockIdx.y;        // 0..31
    int n0 = (tile >> 3) * 128, m0 = (tile & 7) * 128;
    int tid = threadIdx.x, lane = tid & 63, w = tid >> 6;
    int wr = w >> 1, wc = w & 1;
    const ushort* qt = qb + ((size_t)bh * NV + n0) * DH;  // 8KB contiguous
    const ushort* ktb = kb + ((size_t)bh * NV + m0) * DH;
#pragma unroll
    for (int p = 0; p < 2; ++p) {
        int ci = w * 2 + p;
        __builtin_amdgcn_global_load_lds((const __attribute__((address_space(1))) void*)(qt + ci * 512 + lane * 8),
                                         (__attribute__((address_space(3))) void*)(As + ci * 512), 16, 0, 0);
        __builtin_amdgcn_global_load_lds((const __attribute__((address_space(1))) void*)(ktb + ci * 512 + lane * 8),
                                         (__attribute__((address_space(3))) void*)(Bs + ci * 512), 16, 0, 0);
    }
    __syncthreads();
    int cl = lane & 15, q = lane >> 4;
    const ushort* ap = As + ((wr * 64 + cl) * 32 + q * 8);
    const ushort* bp = Bs + ((wc * 64 + cl) * 32 + q * 8);
    short8 af[4], bfr[4];
#pragma unroll
    for (int i = 0; i < 4; ++i) af[i] = *(const short8*)(ap + i * 512);
#pragma unroll
    for (int j = 0; j < 4; ++j) bfr[j] = *(const short8*)(bp + j * 512);
    f32x4 acc[4][4] = {};
#pragma unroll
    for (int i = 0; i < 4; ++i)
#pragma unroll
        for (int j = 0; j < 4; ++j)
            acc[i][j] = __builtin_amdgcn_mfma_f32_16x16x32_bf16(af[i], bfr[j], acc[i][j], 0, 0, 0);
    size_t sb = (size_t)bh * NV * NV;
#pragma unroll
    for (int i = 0; i < 4; ++i) {
        int rbase = n0 + wr * 64 + i * 16 + q * 4;
#pragma unroll
        for (int j = 0; j < 4; ++j) {
            int col = m0 + wc * 64 + j * 16 + cl;
#pragma unroll
            for (int r = 0; r < 4; ++r)
                S[sb + (size_t)(rbase + r) * NV + col] = acc[i][j][r] * 0.17677669529663687f;
        }
    }
}

// ---------------- K5: row softmax, write P bf16 in place over the f32 row ----------------
__global__ __launch_bounds__(256) void k_softmax(float* __restrict__ S) {
    __shared__ float red[4];
    int row = blockIdx.x, t = threadIdx.x, lane = t & 63;
    float* rp = S + (size_t)row * NV;
    float4 v = ((const float4*)rp)[t];
    float m = fmaxf(fmaxf(v.x, v.y), fmaxf(v.z, v.w));
#pragma unroll
    for (int off = 32; off; off >>= 1) m = fmaxf(m, __shfl_xor(m, off));
    if (lane == 0) red[t >> 6] = m;
    __syncthreads();
    m = fmaxf(fmaxf(red[0], red[1]), fmaxf(red[2], red[3]));
    __syncthreads();
    float e0 = __expf(v.x - m), e1 = __expf(v.y - m), e2 = __expf(v.z - m), e3 = __expf(v.w - m);
    float s4 = e0 + e1 + e2 + e3;
#pragma unroll
    for (int off = 32; off; off >>= 1) s4 += __shfl_xor(s4, off);
    if (lane == 0) red[t >> 6] = s4;
    __syncthreads();
    float inv = 1.0f / (red[0] + red[1] + red[2] + red[3]);
    ushort4 o;
    o.x = f2bf(e0 * inv); o.y = f2bf(e1 * inv); o.z = f2bf(e2 * inv); o.w = f2bf(e3 * inv);
    ((ushort4*)rp)[t] = o;
}

// ---------------- K6: O = P V  (M=128 tile, N=32, K=1024) -> obuf [b,n,128] f32 ----------------
__global__ __launch_bounds__(256) void k_pv(const float* __restrict__ Sf, const ushort* __restrict__ vt,
                                            float* __restrict__ obuf) {
    __shared__ ushort As[128 * 32];
    __shared__ ushort Bs[32 * 32];
    int n0 = blockIdx.x * 128, bh = blockIdx.y;
    int b = bh >> 2, h = bh & 3;
    int tid = threadIdx.x, lane = tid & 63, w = tid >> 6;
    const char* Sb = (const char*)Sf;
    const ushort* vtb = vt + (size_t)bh * DH * NV;
    f32x4 acc[2][2] = {};
    for (int kt = 0; kt < NV / 32; ++kt) {
        int k0 = kt * 32;
        __syncthreads();
        // A: P tile 128 x 32 bf16, rows at byte stride 4096 (bf16 packed in f32 row region)
#pragma unroll
        for (int p = 0; p < 2; ++p) {
            int ci = w * 2 + p;
            int rrow = ci * 16 + (lane >> 2);
            int kch = (lane & 3) * 8;
            const ushort* gp = (const ushort*)(Sb + (size_t)(bh * NV + n0 + rrow) * 4096) + k0 + kch;
            __builtin_amdgcn_global_load_lds((const __attribute__((address_space(1))) void*)gp,
                                             (__attribute__((address_space(3))) void*)(As + ci * 512 + (lane >> 2) * 32 + kch - ((lane >> 2) * 32 + kch) + rrow * 32 + kch - ci * 512), 16, 0, 0);
        }
        // B: V^T tile 32 x 32 bf16
        if (tid < 128) {
            int d = tid >> 2, ch = tid & 3;
            short8 u = *(const short8*)(vtb + (size_t)d * NV + k0 + ch * 8);
            *(short8*)(&Bs[d * 32 + ch * 8]) = u;
        }
        __syncthreads();
        int cl = lane & 15, q = lane >> 4;
        const ushort* ap = As + ((w * 32 + cl) * 32 + q * 8);
        const ushort* bp = Bs + (cl * 32 + q * 8);
        short8 af[2], bfr[2];
#pragma unroll
        for (int i = 0; i < 2; ++i) af[i] = *(const short8*)(ap + i * 512);
#pragma unroll
        for (int j = 0; j < 2; ++j) bfr[j] = *(const short8*)(bp + j * 512);
#pragma unroll
        for (int i = 0; i < 2; ++i)
#pragma unroll
            for (int j = 0; j < 2; ++j)
                acc[i][j] = __builtin_amdgcn_mfma_f32_16x16x32_bf16(af[i], bfr[j], acc[i][j], 0, 0, 0);
    }
    int cl = lane & 15, q = lane >> 4;
#pragma unroll
    for (int i = 0; i < 2; ++i) {
        int rbase = n0 + w * 32 + i * 16 + q * 4;
#pragma unroll
        for (int j = 0; j < 2; ++j) {
            int d = j * 16 + cl;
#pragma unroll
            for (int r = 0; r < 4; ++r)
                obuf[((size_t)(b * NV + rbase + r)) * HH + h * DH + d] = acc[i][j][r];
        }
    }
}

// ---------------- K7: output projection + residual ----------------
__global__ void k_proj(const float* __restrict__ o, const float* __restrict__ W,
                       const float* __restrict__ bias, float* __restrict__ eig) {
    __shared__ float xr[HH];
    int row = blockIdx.x, t = threadIdx.x;
    xr[t] = o[(size_t)row * HH + t];
    __syncthreads();
    const float* wr = W + (size_t)t * HH;
    float acc = bias[t];
    for (int j = 0; j < HH; ++j) acc += xr[j] * wr[j];
    eig[(size_t)row * HH + t] += acc;
}

// ---------------- K8: LN2 + FFN + residual ----------------
__global__ void k_ffn(float* __restrict__ eig, const float* __restrict__ g2, const float* __restrict__ bv,
                      const float* __restrict__ W1, const float* __restrict__ b1,
                      const float* __restrict__ W2, const float* __restrict__ b2) {
    __shared__ float x[HH];
    __shared__ float hbuf[HH];
    __shared__ float tmp[2];
    int row = blockIdx.x, t = threadIdx.x;
    float e = eig[(size_t)row * HH + t];
    float mean = block_sum_128(e, tmp, t) * (1.0f / HH);
    float d = e - mean;
    float var = block_sum_128(d * d, tmp, t) * (1.0f / HH);
    x[t] = d * rsqrtf(var + 1e-5f) * g2[t] + bv[t];
    __syncthreads();
    const float* w1 = W1 + (size_t)t * HH;
    float a = b1[t];
    for (int j = 0; j < HH; ++j) a += x[j] * w1[j];
    float ge = 0.5f * a * (1.0f + erff(a * 0.7071067811865475f));  // exact gelu
    hbuf[t] = ge;
    __syncthreads();
    const float* w2 = W2 + (size_t)t * HH;
    float y = b2[t];
    for (int j = 0; j < HH; ++j) y += hbuf[j] * w2[j];
    eig[(size_t)row * HH + t] = e + y;
}

// ---------------- K9: mean pool over N ----------------
__global__ void k_meanpool(const float* __restrict__ eig, float* __restrict__ me) {
    int b = blockIdx.x, t = threadIdx.x;
    float s = 0.f;
    const float* p = eig + (size_t)b * NV * HH + t;
    for (int n = 0; n < NV; ++n) s += p[(size_t)n * HH];
    me[b * HH + t] = s * (1.0f / NV);
}

// ---------------- K10: decoders (sigmoid + normalize) ----------------
__global__ void k_decoders(const float* __restrict__ me,
                           const float* __restrict__ dscW, const float* __restrict__ dscb,
                           const float* __restrict__ dwavW, const float* __restrict__ dwavb,
                           const float* __restrict__ dsclW, const float* __restrict__ dsclb,
                           float* __restrict__ cs, float* __restrict__ cw, float* __restrict__ csc) {
    __shared__ float m[HH];
    __shared__ float s1[NCOE], s2[NCOE];
    __shared__ float sums[2];
    int b = blockIdx.x, t = threadIdx.x;  // 64 threads
    m[t] = me[b * HH + t];
    m[t + 64] = me[b * HH + t + 64];
    __syncthreads();
    if (t < NCOE) {
        float a = dscb[t], a2 = dwavb[t];
        const float* w1 = dscW + t * HH;
        const float* w2 = dwavW + t * HH;
        for (int j = 0; j < HH; ++j) { a += m[j] * w1[j]; a2 += m[j] * w2[j]; }
        s1[t] = 1.f / (1.f + __expf(-a));
        s2[t] = 1.f / (1.f + __expf(-a2));
    }
    if (t < NSC) {
        float a = dsclb[t];
        const float* wv = dsclW + t * HH;
        for (int j = 0; j < HH; ++j) a += m[j] * wv[j];
        csc[b * NSC + t] = 5.0f / (1.f + __expf(-a));  // THRE * sigmoid
    }
    __syncthreads();
    if (t == 0) {
        float a = 0.f, bb = 0.f;
        for (int c = 0; c < NCOE; ++c) { a += s1[c]; bb += s2[c]; }
        sums[0] = a; sums[1] = bb;
    }
    __syncthreads();
    if (t < NCOE) {
        cs[b * NCOE + t] = s1[t] / (sums[0] + 1e-8f);
        cw[b * NCOE + t] = s2[t] / (sums[1] + 1e-8f);
    }
}

// ---------------- K11: Chebyshev recurrences -> fsaT [B,5,N] (normalized) ----------------
__global__ void k_fsa(const float* __restrict__ ev, const float* __restrict__ cs,
                      const float* __restrict__ cw, const float* __restrict__ csc,
                      float* __restrict__ fsaT) {
    __shared__ float lcs[NCOE], lcw[NCOE], lsc[NSC];
    int gid = blockIdx.x * 256 + threadIdx.x;
    int b = gid >> 10, n = gid & (NV - 1);
    int t = threadIdx.x;
    if (t < NCOE) { lcs[t] = cs[b * NCOE + t]; lcw[t] = cw[b * NCOE + t]; }
    if (t < NSC) lsc[t] = csc[b * NSC + t];
    __syncthreads();
    float e = ev[gid];
    float x = e - 1.0f;
    float te = 1.f, to = x;
    float a0 = lcs[0] * 0.5f * (1.f - to);
    for (int c = 1; c < NCOE; ++c) {
        te = 2.f * x * to - te;
        to = 2.f * x * te - to;
        a0 += lcs[c] * 0.5f * (1.f - to);
    }
    float aw[NSC];
#pragma unroll
    for (int s = 0; s < NSC; ++s) {
        float f = e * lsc[s];
        if (f > 2.0f) f = 0.0f;
        float y = f - 1.0f;
        float te2 = 1.f, to2 = y, a = 0.f;
        for (int c = 1; c < NCOE; ++c) {
            te2 = 2.f * y * to2 - te2;
            to2 = 2.f * y * te2 - to2;
            a += lcw[c] * 0.5f * (1.f - te2);
        }
        aw[s] = a;
    }
    float n2 = a0 * a0;
#pragma unroll
    for (int s = 0; s < NSC; ++s) n2 += aw[s] * aw[s];
    float inv = 1.f / (sqrtf(n2) + 1e-8f);
    fsaT[((size_t)b * 5 + 0) * NV + n] = a0 * inv;
#pragma unroll
    for (int s = 0; s < NSC; ++s) fsaT[((size_t)b * 5 + 1 + s) * NV + n] = aw[s] * inv;
}

// ---------------- K12: eigenvector f32 -> bf16 ----------------
__global__ void k_tobf16(const float* __restrict__ in, ushort* __restrict__ outp) {
    int i = blockIdx.x * 256 + threadIdx.x;
    const float4* p = (const float4*)in + (size_t)i * 2;
    float4 a = p[0], bq = p[1];
    uint4 r;
    r.x = (uint)f2bf(a.x) | ((uint)f2bf(a.y) << 16);
    r.y = (uint)f2bf(a.z) | ((uint)f2bf(a.w) << 16);
    r.z = (uint)f2bf(bq.x) | ((uint)f2bf(bq.y) << 16);
    r.w = (uint)f2bf(bq.z) | ((uint)f2bf(bq.w) << 16);
    ((uint4*)outp)[i] = r;
}

// ---------------- K13: batched GEMM  C[n,m] = sum_k (V[n,k]*fsa[k]) * V[m,k] ----------------
__global__ __launch_bounds__(256) void k_gemm(const ushort* __restrict__ Vb,
                                              const float* __restrict__ fsaT,
                                              float* __restrict__ out,
                                              float* __restrict__ cn) {
    __shared__ ushort As[128 * 32];
    __shared__ ushort Bs[128 * 32];
    int tile = blockIdx.x;      // 0..63
    int bsid = blockIdx.y;      // 0..39
    int b = bsid / 5, s = bsid % 5;
    int n0 = (tile >> 3) * 128, m0 = (tile & 7) * 128;
    int tid = threadIdx.x, lane = tid & 63, w = tid >> 6;
    int wr = w >> 1, wc = w & 1;
    const ushort* Vbase = Vb + (size_t)b * NV * NV;
    const float* fs = fsaT + ((size_t)b * 5 + s) * NV;
    f32x4 acc[4][4] = {};

    for (int kt = 0; kt < NV / 32; ++kt) {
        int k0 = kt * 32;
        __syncthreads();
#pragma unroll
        for (int p = 0; p < 2; ++p) {
            int ci = w * 2 + p;
            int rrow = ci * 16 + (lane >> 2);
            int kch = (lane & 3) * 8;
            const ushort* gp = Vbase + (size_t)(m0 + rrow) * NV + k0 + kch;
            __builtin_amdgcn_global_load_lds((const __attribute__((address_space(1))) void*)gp,
                                             (__attribute__((address_space(3))) void*)(Bs + ci * 512),
                                             16, 0, 0);
        }
#pragma unroll
        for (int p = 0; p < 2; ++p) {
            int idx = p * 256 + tid;
            int rrow = idx >> 2;
            int kch = (idx & 3) * 8;
            const ushort* gp = Vbase + (size_t)(n0 + rrow) * NV + k0 + kch;
            uint4 raw = *(const uint4*)gp;
            const float4* fp = (const float4*)(fs + k0 + kch);
            float4 f0 = fp[0], f1 = fp[1];
            float v0 = __uint_as_float(raw.x << 16) * f0.x;
            float v1 = __uint_as_float(raw.x & 0xffff0000u) * f0.y;
            float v2 = __uint_as_float(raw.y << 16) * f0.z;
            float v3 = __uint_as_float(raw.y & 0xffff0000u) * f0.w;
            float v4 = __uint_as_float(raw.z << 16) * f1.x;
            float v5 = __uint_as_float(raw.z & 0xffff0000u) * f1.y;
            float v6 = __uint_as_float(raw.w << 16) * f1.z;
            float v7 = __uint_as_float(raw.w & 0xffff0000u) * f1.w;
            uint4 rr;
            rr.x = (uint)f2bf(v0) | ((uint)f2bf(v1) << 16);
            rr.y = (uint)f2bf(v2) | ((uint)f2bf(v3) << 16);
            rr.z = (uint)f2bf(v4) | ((uint)f2bf(v5) << 16);
            rr.w = (uint)f2bf(v6) | ((uint)f2bf(v7) << 16);
            *(uint4*)(As + rrow * 32 + kch) = rr;
        }
        __syncthreads();
        int cl = lane & 15, q = lane >> 4;
        const ushort* ap = As + ((wr * 64 + cl) * 32 + q * 8);
        const ushort* bp = Bs + ((wc * 64 + cl) * 32 + q * 8);
        short8 af[4], bfr[4];
#pragma unroll
        for (int i = 0; i < 4; ++i) af[i] = *(const short8*)(ap + i * 512);
#pragma unroll
        for (int j = 0; j < 4; ++j) bfr[j] = *(const short8*)(bp + j * 512);
#pragma unroll
        for (int i = 0; i < 4; ++i)
#pragma unroll
            for (int j = 0; j < 4; ++j)
                acc[i][j] = __builtin_amdgcn_mfma_f32_16x16x32_bf16(af[i], bfr[j], acc[i][j], 0, 0, 0);
    }
    int cl = lane & 15, q = lane >> 4;
    size_t ob = (size_t)(s * BB + b) * NV * NV;
    float colss[4] = {0.f, 0.f, 0.f, 0.f};
#pragma unroll
    for (int i = 0; i < 4; ++i) {
        int rbase = n0 + wr * 64 + i * 16 + q * 4;
#pragma unroll
        for (int j = 0; j < 4; ++j) {
            int col = m0 + wc * 64 + j * 16 + cl;
#pragma unroll
            for (int r = 0; r < 4; ++r) {
                float v = acc[i][j][r];
                out[ob + (size_t)(rbase + r) * NV + col] = v;
                colss[j] += v * v;
            }
        }
    }
    float* cnb = cn + (size_t)(s * BB + b) * NV;
#pragma unroll
    for (int j = 0; j < 4; ++j) {
        float v = colss[j];
        v += __shfl_xor(v, 16);
        v += __shfl_xor(v, 32);
        if (q == 0) atomicAdd(cnb + (m0 + wc * 64 + j * 16 + cl), v);
    }
}

// ---------------- K14: in-place column normalization ----------------
__global__ void k_norm(float* __restrict__ out, const float* __restrict__ cn) {
    int bid = blockIdx.x;
    int bs = bid >> 10, n = bid & (NV - 1);
    int m4 = threadIdx.x * 4;
    float4 ssv = *(const float4*)(cn + (size_t)bs * NV + m4);
    float4* p = (float4*)(out + ((size_t)bs * NV + n) * NV + m4);
    float4 v = *p;
    v.x *= 1.f / fmaxf(sqrtf(ssv.x), 1e-12f);
    v.y *= 1.f / fmaxf(sqrtf(ssv.y), 1e-12f);
    v.z *= 1.f / fmaxf(sqrtf(ssv.z), 1e-12f);
    v.w *= 1.f / fmaxf(sqrtf(ssv.w), 1e-12f);
    *p = v;
}

extern "C" void kernel_launch(void* const* d_in, const int* in_sizes, int n_in,
                              void* d_out, int out_size, void* d_ws, size_t ws_size,
                              hipStream_t stream) {
    const float* eigenvalue = (const float*)d_in[0];
    const float* eigenvector = (const float*)d_in[1];
    const float* eigw_W = (const float*)d_in[2];
    const float* eigw_b = (const float*)d_in[3];
    const float* ln1_g = (const float*)d_in[4];
    const float* ln1_b = (const float*)d_in[5];
    const float* qkv_W = (const float*)d_in[6];
    const float* qkv_b = (const float*)d_in[7];
    const float* out_W = (const float*)d_in[8];
    const float* out_b = (const float*)d_in[9];
    const float* ln2_g = (const float*)d_in[10];
    const float* ln2_b = (const float*)d_in[11];
    const float* ffn1_W = (const float*)d_in[12];
    const float* ffn1_b = (const float*)d_in[13];
    const float* ffn2_W = (const float*)d_in[14];
    const float* ffn2_b = (const float*)d_in[15];
    const float* dsc_W = (const float*)d_in[16];
    const float* dsc_b = (const float*)d_in[17];
    const float* dwav_W = (const float*)d_in[18];
    const float* dwav_b = (const float*)d_in[19];
    const float* dscl_W = (const float*)d_in[20];
    const float* dscl_b = (const float*)d_in[21];

    char* w = (char*)d_ws;
    float* eig  = (float*)(w + 0);             // 4,194,304
    float* me   = (float*)(w + 4194304);       // 4 KB
    float* cs   = (float*)(w + 4198400);       // 2 KB
    float* cw   = (float*)(w + 4200448);       // 2 KB
    float* csc  = (float*)(w + 4202496);       // 1 KB
    float* fsaT = (float*)(w + 4203520);       // 160 KB
    float* cn   = (float*)(w + 4367360);       // 160 KB
    ushort* qb  = (ushort*)(w + 4531200);      // 2 MB
    ushort* kb  = (ushort*)(w + 6628352);      // 2 MB
    ushort* vb  = (ushort*)(w + 8725504);      // 2 MB
    ushort* vt  = (ushort*)(w + 10822656);     // 2 MB
    float* obuf = (float*)(w + 12919808);      // 4 MB
    ushort* Vb  = (ushort*)(w + 17114112);     // 16 MB -> end 33,891,328

    float* outp = (float*)d_out;
    float* S = (float*)d_out;   // scratch: 32 MB f32 region, overwritten later by k_gemm

    hipMemsetAsync(cn, 0, 40 * NV * sizeof(float), stream);

    k_sine_linear<<<dim3(BB * NV), dim3(HH), 0, stream>>>(eigenvalue, eigw_W, eigw_b, eig);
    k_ln_qkv<<<dim3(BB * NV), dim3(HH), 0, stream>>>(eig, ln1_g, ln1_b, qkv_W, qkv_b, qb, kb, vb);
    k_vt<<<dim3(4, 32), dim3(256), 0, stream>>>(vb, vt);
    k_qk<<<dim3(64, 32), dim3(256), 0, stream>>>(qb, kb, S);
    k_softmax<<<dim3(32 * NV), dim3(256), 0, stream>>>(S);
    k_pv<<<dim3(8, 32), dim3(256), 0, stream>>>(S, vt, obuf);
    k_proj<<<dim3(BB * NV), dim3(HH), 0, stream>>>(obuf, out_W, out_b, eig);
    k_ffn<<<dim3(BB * NV), dim3(HH), 0, stream>>>(eig, ln2_g, ln2_b, ffn1_W, ffn1_b, ffn2_W, ffn2_b);
    k_meanpool<<<dim3(BB), dim3(HH), 0, stream>>>(eig, me);
    k_decoders<<<dim3(BB), dim3(64), 0, stream>>>(me, dsc_W, dsc_b, dwav_W, dwav_b, dscl_W, dscl_b, cs, cw, csc);
    k_fsa<<<dim3(BB * NV / 256), dim3(256), 0, stream>>>(eigenvalue, cs, cw, csc, fsaT);
    k_tobf16<<<dim3(BB * NV * NV / (8 * 256)), dim3(256), 0, stream>>>(eigenvector, Vb);
    k_gemm<<<dim3(64, 40), dim3(256), 0, stream>>>(Vb, fsaT, outp, cn);
    k_norm<<<dim3(40 * NV), dim3(256), 0, stream>>>(outp, cn);
}

// Round 3
// 567.133 us; speedup vs baseline: 3.1648x; 1.6614x over previous
//
#include <hip/hip_runtime.h>
#include <hip/hip_bf16.h>
#include <cstdint>

#define BB 8
#define NV 1024
#define HH 128
#define DH 32
#define NCOE 50
#define NSC 4

// Wb segment offsets (elements)
#define WOFF_EIG 0
#define WOFF_QKV 16384
#define WOFF_OUT 65536
#define WOFF_F1  81920
#define WOFF_F2  98304
#define WB_ELEMS 114688

typedef __attribute__((ext_vector_type(8))) short short8;
typedef __attribute__((ext_vector_type(4))) float f32x4;

__device__ __forceinline__ ushort f2bf(float f) {
    uint32_t x = __float_as_uint(f);
    uint32_t r = x + 0x7FFFu + ((x >> 16) & 1u);
    return (ushort)(r >> 16);
}

#define GLDS(gp, lp) __builtin_amdgcn_global_load_lds((const __attribute__((address_space(1))) void*)(gp), (__attribute__((address_space(3))) void*)(lp), 16, 0, 0)

// ---------------- K0: weight convert f32 -> bf16, LDS-chunked layout [kt][r][32] ----------------
__global__ void k_wcvt(const float* __restrict__ eigw_W, const float* __restrict__ qkv_W,
                       const float* __restrict__ out_W, const float* __restrict__ f1W,
                       const float* __restrict__ f2W, ushort* __restrict__ Wb) {
    int idx = blockIdx.x * 256 + threadIdx.x;
    float v; int dst;
    if (idx < 16384) {                 // eigw cols 1..128
        int r = idx >> 7, k = idx & 127;
        v = eigw_W[r * 129 + 1 + k];
        dst = WOFF_EIG + (k >> 5) * 4096 + r * 32 + (k & 31);
    } else if (idx < 65536) {          // qkv_W, 3 chunks of 128 rows
        int l = idx - 16384; int c = l >> 14, rem = l & 16383;
        int r = rem >> 7, k = rem & 127;
        v = qkv_W[(size_t)(c * 128 + r) * 128 + k];
        dst = WOFF_QKV + c * 16384 + (k >> 5) * 4096 + r * 32 + (k & 31);
    } else if (idx < 81920) {          // out_W
        int l = idx - 65536; int r = l >> 7, k = l & 127;
        v = out_W[r * 128 + k];
        dst = WOFF_OUT + (k >> 5) * 4096 + r * 32 + (k & 31);
    } else if (idx < 98304) {          // ffn1_W
        int l = idx - 81920; int r = l >> 7, k = l & 127;
        v = f1W[r * 128 + k];
        dst = WOFF_F1 + (k >> 5) * 4096 + r * 32 + (k & 31);
    } else {                           // ffn2_W
        int l = idx - 98304; int r = l >> 7, k = l & 127;
        v = f2W[r * 128 + k];
        dst = WOFF_F2 + (k >> 5) * 4096 + r * 32 + (k & 31);
    }
    Wb[dst] = f2bf(v);
}

// ---------------- K1: sine encoding + eigw linear (MFMA) -> eig f32 [8192][128] ----------------
__global__ __launch_bounds__(256) void k_enc_sine(const float* __restrict__ ev, const ushort* __restrict__ Wb,
                                                  const float* __restrict__ eigw_W, const float* __restrict__ eigw_b,
                                                  float* __restrict__ eig) {
    __shared__ ushort As[16384];
    __shared__ ushort Bs[16384];
    int row0 = blockIdx.x * 128;
    int t = threadIdx.x, lane = t & 63, w = t >> 6;
    int wr = w >> 1, wc = w & 1;
#pragma unroll
    for (int p = 0; p < 8; ++p) {
        int ci = w * 8 + p;
        GLDS(Wb + WOFF_EIG + ci * 512 + lane * 8, Bs + ci * 512);
    }
    {
        int r = t >> 1, half = t & 1;
        float e = ev[row0 + r] * 100.0f;
#pragma unroll
        for (int ch = 0; ch < 8; ++ch) {
            short8 u;
#pragma unroll
            for (int l = 0; l < 8; ++l) {
                int j = ch * 8 + l;
                float div = expf((float)(2 * j) * -0.07195578415606394f);
                float pe = e * div;
                u[l] = (short)f2bf(half ? cosf(pe) : sinf(pe));
            }
            int k = half * 64 + ch * 8;
            *(short8*)(As + (k >> 5) * 4096 + r * 32 + (k & 31)) = u;
        }
    }
    __syncthreads();
    int cl = lane & 15, q = lane >> 4;
    f32x4 acc[4][4] = {};
#pragma unroll
    for (int kt = 0; kt < 4; ++kt) {
        const ushort* ap = As + kt * 4096 + (wr * 64 + cl) * 32 + q * 8;
        const ushort* bp = Bs + kt * 4096 + (wc * 64 + cl) * 32 + q * 8;
        short8 af[4], bfr[4];
#pragma unroll
        for (int i = 0; i < 4; ++i) af[i] = *(const short8*)(ap + i * 512);
#pragma unroll
        for (int j = 0; j < 4; ++j) bfr[j] = *(const short8*)(bp + j * 512);
#pragma unroll
        for (int i = 0; i < 4; ++i)
#pragma unroll
            for (int j = 0; j < 4; ++j)
                acc[i][j] = __builtin_amdgcn_mfma_f32_16x16x32_bf16(af[i], bfr[j], acc[i][j], 0, 0, 0);
    }
#pragma unroll
    for (int i = 0; i < 4; ++i) {
        int rbase = wr * 64 + i * 16 + q * 4;
        float er[4];
#pragma unroll
        for (int r = 0; r < 4; ++r) er[r] = ev[row0 + rbase + r];
#pragma unroll
        for (int j = 0; j < 4; ++j) {
            int col = wc * 64 + j * 16 + cl;
            float w0 = eigw_W[col * 129];
            float bv = eigw_b[col];
#pragma unroll
            for (int r = 0; r < 4; ++r)
                eig[(size_t)(row0 + rbase + r) * HH + col] = acc[i][j][r] + er[r] * w0 + bv;
        }
    }
}

// ---------------- K2: LN1 + QKV (MFMA) -> q/k/v bf16 head-major [bh][n][32] ----------------
__global__ __launch_bounds__(256) void k_enc_qkv(const float* __restrict__ eig, const float* __restrict__ g,
                                                 const float* __restrict__ be, const ushort* __restrict__ Wb,
                                                 const float* __restrict__ bias,
                                                 ushort* __restrict__ qb, ushort* __restrict__ kb, ushort* __restrict__ vb) {
    __shared__ ushort As[16384];
    __shared__ ushort Bs[16384];
    int row0 = blockIdx.x * 128;
    int t = threadIdx.x, lane = t & 63, w = t >> 6;
    int wr = w >> 1, wc = w & 1;
    {
        int r = t >> 1, half = t & 1;
        const float4* rowp = (const float4*)(eig + (size_t)(row0 + r) * HH + half * 64);
        float4 v[16];
        float s = 0.f, s2 = 0.f;
#pragma unroll
        for (int i = 0; i < 16; ++i) {
            float4 a = rowp[i]; v[i] = a;
            s += a.x + a.y + a.z + a.w;
            s2 += a.x * a.x + a.y * a.y + a.z * a.z + a.w * a.w;
        }
        s += __shfl_xor(s, 1); s2 += __shfl_xor(s2, 1);
        float mean = s * 0.0078125f;
        float var = s2 * 0.0078125f - mean * mean;
        float rstd = rsqrtf(var + 1e-5f);
        const float4* g4 = (const float4*)(g + half * 64);
        const float4* b4 = (const float4*)(be + half * 64);
#pragma unroll
        for (int ch = 0; ch < 8; ++ch) {
            float4 a = v[2 * ch], b2 = v[2 * ch + 1];
            float4 ga = g4[2 * ch], gb = g4[2 * ch + 1];
            float4 ba = b4[2 * ch], bb = b4[2 * ch + 1];
            short8 u;
            u[0] = (short)f2bf((a.x - mean) * rstd * ga.x + ba.x);
            u[1] = (short)f2bf((a.y - mean) * rstd * ga.y + ba.y);
            u[2] = (short)f2bf((a.z - mean) * rstd * ga.z + ba.z);
            u[3] = (short)f2bf((a.w - mean) * rstd * ga.w + ba.w);
            u[4] = (short)f2bf((b2.x - mean) * rstd * gb.x + bb.x);
            u[5] = (short)f2bf((b2.y - mean) * rstd * gb.y + bb.y);
            u[6] = (short)f2bf((b2.z - mean) * rstd * gb.z + bb.z);
            u[7] = (short)f2bf((b2.w - mean) * rstd * gb.w + bb.w);
            int k = half * 64 + ch * 8;
            *(short8*)(As + (k >> 5) * 4096 + r * 32 + (k & 31)) = u;
        }
    }
    int cl = lane & 15, q = lane >> 4;
    int bidx = row0 >> 10, nbase = row0 & (NV - 1);
    ushort* dsts[3] = {qb, kb, vb};
#pragma unroll 1
    for (int c = 0; c < 3; ++c) {
        __syncthreads();
#pragma unroll
        for (int p = 0; p < 8; ++p) {
            int ci = w * 8 + p;
            GLDS(Wb + WOFF_QKV + c * 16384 + ci * 512 + lane * 8, Bs + ci * 512);
        }
        __syncthreads();
        f32x4 acc[4][4] = {};
#pragma unroll
        for (int kt = 0; kt < 4; ++kt) {
            const ushort* ap = As + kt * 4096 + (wr * 64 + cl) * 32 + q * 8;
            const ushort* bp = Bs + kt * 4096 + (wc * 64 + cl) * 32 + q * 8;
            short8 af[4], bfr[4];
#pragma unroll
            for (int i = 0; i < 4; ++i) af[i] = *(const short8*)(ap + i * 512);
#pragma unroll
            for (int j = 0; j < 4; ++j) bfr[j] = *(const short8*)(bp + j * 512);
#pragma unroll
            for (int i = 0; i < 4; ++i)
#pragma unroll
                for (int j = 0; j < 4; ++j)
                    acc[i][j] = __builtin_amdgcn_mfma_f32_16x16x32_bf16(af[i], bfr[j], acc[i][j], 0, 0, 0);
        }
        ushort* dst = dsts[c];
#pragma unroll
        for (int j = 0; j < 4; ++j) {
            int col = wc * 64 + j * 16 + cl;
            float bv = bias[c * 128 + col];
            int h = col >> 5, dd = col & 31;
            ushort* hb = dst + ((size_t)(bidx * 4 + h) * NV + nbase) * DH + dd;
#pragma unroll
            for (int i = 0; i < 4; ++i) {
                int rbase = wr * 64 + i * 16 + q * 4;
#pragma unroll
                for (int r = 0; r < 4; ++r)
                    hb[(size_t)(rbase + r) * DH] = f2bf(acc[i][j][r] + bv);
            }
        }
    }
}

// ---------------- K3: V transpose -> vt [bh][32][1024] bf16 ----------------
__global__ __launch_bounds__(256) void k_vt(const ushort* __restrict__ vb, ushort* __restrict__ vt) {
    __shared__ ushort Ld[256 * 40];
    int bh = blockIdx.y, n0 = blockIdx.x * 256;
    int t = threadIdx.x;
    const ushort* src = vb + ((size_t)bh * NV + n0) * DH;
#pragma unroll
    for (int p = 0; p < 4; ++p) {
        int idx = p * 256 + t;
        int rowi = idx >> 2, ch = idx & 3;
        short8 u = *(const short8*)(src + idx * 8);
        *(short8*)(&Ld[rowi * 40 + ch * 8]) = u;
    }
    __syncthreads();
    int d = t >> 3, nc = (t & 7) * 32;
    ushort* dst = vt + ((size_t)bh * DH + d) * NV + n0 + nc;
#pragma unroll
    for (int p = 0; p < 4; ++p) {
        short8 u;
#pragma unroll
        for (int i = 0; i < 8; ++i) u[i] = (short)Ld[(nc + p * 8 + i) * 40 + d];
        *(short8*)(dst + p * 8) = u;
    }
}

// ---------------- K4: S = Q K^T / sqrt(dh) -> S f32 (d_out scratch) ----------------
__global__ __launch_bounds__(256) void k_qk(const ushort* __restrict__ qb, const ushort* __restrict__ kb,
                                            float* __restrict__ S) {
    __shared__ ushort As[128 * 32];
    __shared__ ushort Bs[128 * 32];
    int tile = blockIdx.x;
    int bh = blockIdx.y;
    int n0 = (tile >> 3) * 128, m0 = (tile & 7) * 128;
    int tid = threadIdx.x, lane = tid & 63, w = tid >> 6;
    int wr = w >> 1, wc = w & 1;
    const ushort* qt = qb + ((size_t)bh * NV + n0) * DH;
    const ushort* ktb = kb + ((size_t)bh * NV + m0) * DH;
#pragma unroll
    for (int p = 0; p < 2; ++p) {
        int ci = w * 2 + p;
        GLDS(qt + ci * 512 + lane * 8, As + ci * 512);
        GLDS(ktb + ci * 512 + lane * 8, Bs + ci * 512);
    }
    __syncthreads();
    int cl = lane & 15, q = lane >> 4;
    const ushort* ap = As + ((wr * 64 + cl) * 32 + q * 8);
    const ushort* bp = Bs + ((wc * 64 + cl) * 32 + q * 8);
    short8 af[4], bfr[4];
#pragma unroll
    for (int i = 0; i < 4; ++i) af[i] = *(const short8*)(ap + i * 512);
#pragma unroll
    for (int j = 0; j < 4; ++j) bfr[j] = *(const short8*)(bp + j * 512);
    f32x4 acc[4][4] = {};
#pragma unroll
    for (int i = 0; i < 4; ++i)
#pragma unroll
        for (int j = 0; j < 4; ++j)
            acc[i][j] = __builtin_amdgcn_mfma_f32_16x16x32_bf16(af[i], bfr[j], acc[i][j], 0, 0, 0);
    size_t sb = (size_t)bh * NV * NV;
#pragma unroll
    for (int i = 0; i < 4; ++i) {
        int rbase = n0 + wr * 64 + i * 16 + q * 4;
#pragma unroll
        for (int j = 0; j < 4; ++j) {
            int col = m0 + wc * 64 + j * 16 + cl;
#pragma unroll
            for (int r = 0; r < 4; ++r)
                S[sb + (size_t)(rbase + r) * NV + col] = acc[i][j][r] * 0.17677669529663687f;
        }
    }
}

// ---------------- K5: row softmax, P bf16 written in place ----------------
__global__ __launch_bounds__(256) void k_softmax(float* __restrict__ S) {
    __shared__ float red[4];
    int row = blockIdx.x, t = threadIdx.x, lane = t & 63;
    float* rp = S + (size_t)row * NV;
    float4 v = ((const float4*)rp)[t];
    float m = fmaxf(fmaxf(v.x, v.y), fmaxf(v.z, v.w));
#pragma unroll
    for (int off = 32; off; off >>= 1) m = fmaxf(m, __shfl_xor(m, off));
    if (lane == 0) red[t >> 6] = m;
    __syncthreads();
    m = fmaxf(fmaxf(red[0], red[1]), fmaxf(red[2], red[3]));
    __syncthreads();
    float e0 = __expf(v.x - m), e1 = __expf(v.y - m), e2 = __expf(v.z - m), e3 = __expf(v.w - m);
    float s4 = e0 + e1 + e2 + e3;
#pragma unroll
    for (int off = 32; off; off >>= 1) s4 += __shfl_xor(s4, off);
    if (lane == 0) red[t >> 6] = s4;
    __syncthreads();
    float inv = 1.0f / (red[0] + red[1] + red[2] + red[3]);
    ushort4 o;
    o.x = f2bf(e0 * inv); o.y = f2bf(e1 * inv); o.z = f2bf(e2 * inv); o.w = f2bf(e3 * inv);
    ((ushort4*)rp)[t] = o;
}

// ---------------- K6: O = P V -> obuf bf16 [8192][128] ----------------
__global__ __launch_bounds__(256) void k_pv(const float* __restrict__ Sf, const ushort* __restrict__ vt,
                                            ushort* __restrict__ obuf) {
    __shared__ ushort As[128 * 32];
    __shared__ ushort Bs[32 * 32];
    int n0 = blockIdx.x * 128, bh = blockIdx.y;
    int b = bh >> 2, h = bh & 3;
    int tid = threadIdx.x, lane = tid & 63, w = tid >> 6;
    const char* Sb = (const char*)Sf;
    const ushort* vtb = vt + (size_t)bh * DH * NV;
    f32x4 acc[2][2] = {};
    for (int kt = 0; kt < NV / 32; ++kt) {
        int k0 = kt * 32;
        __syncthreads();
#pragma unroll
        for (int p = 0; p < 2; ++p) {
            int ci = w * 2 + p;
            int rrow = ci * 16 + (lane >> 2);
            int kch = (lane & 3) * 8;
            const ushort* gp = (const ushort*)(Sb + (size_t)(bh * NV + n0 + rrow) * 4096) + k0 + kch;
            GLDS(gp, As + ci * 512);
        }
        if (tid < 128) {
            int d = tid >> 2, ch = tid & 3;
            short8 u = *(const short8*)(vtb + (size_t)d * NV + k0 + ch * 8);
            *(short8*)(&Bs[d * 32 + ch * 8]) = u;
        }
        __syncthreads();
        int cl = lane & 15, q = lane >> 4;
        const ushort* ap = As + ((w * 32 + cl) * 32 + q * 8);
        const ushort* bp = Bs + (cl * 32 + q * 8);
        short8 af[2], bfr[2];
#pragma unroll
        for (int i = 0; i < 2; ++i) af[i] = *(const short8*)(ap + i * 512);
#pragma unroll
        for (int j = 0; j < 2; ++j) bfr[j] = *(const short8*)(bp + j * 512);
#pragma unroll
        for (int i = 0; i < 2; ++i)
#pragma unroll
            for (int j = 0; j < 2; ++j)
                acc[i][j] = __builtin_amdgcn_mfma_f32_16x16x32_bf16(af[i], bfr[j], acc[i][j], 0, 0, 0);
    }
    int cl = lane & 15, q = lane >> 4;
#pragma unroll
    for (int i = 0; i < 2; ++i) {
        int rbase = n0 + w * 32 + i * 16 + q * 4;
#pragma unroll
        for (int j = 0; j < 2; ++j) {
            int d = j * 16 + cl;
#pragma unroll
            for (int r = 0; r < 4; ++r)
                obuf[((size_t)(b * NV + rbase + r)) * HH + h * DH + d] = f2bf(acc[i][j][r]);
        }
    }
}

// ---------------- K7: proj (MFMA) + residual -> eig ----------------
__global__ __launch_bounds__(256) void k_enc_proj(const ushort* __restrict__ obuf, const ushort* __restrict__ Wb,
                                                  const float* __restrict__ bias, float* __restrict__ eig) {
    __shared__ ushort As[16384];
    __shared__ ushort Bs[16384];
    int row0 = blockIdx.x * 128;
    int t = threadIdx.x, lane = t & 63, w = t >> 6;
    int wr = w >> 1, wc = w & 1;
#pragma unroll
    for (int p = 0; p < 8; ++p) {
        int ci = w * 8 + p;
        int kt = ci >> 3, rb = ci & 7;
        const ushort* gp = obuf + (size_t)(row0 + rb * 16 + (lane >> 2)) * HH + kt * 32 + (lane & 3) * 8;
        GLDS(gp, As + kt * 4096 + rb * 512);
        GLDS(Wb + WOFF_OUT + ci * 512 + lane * 8, Bs + ci * 512);
    }
    __syncthreads();
    int cl = lane & 15, q = lane >> 4;
    f32x4 acc[4][4] = {};
#pragma unroll
    for (int kt = 0; kt < 4; ++kt) {
        const ushort* ap = As + kt * 4096 + (wr * 64 + cl) * 32 + q * 8;
        const ushort* bp = Bs + kt * 4096 + (wc * 64 + cl) * 32 + q * 8;
        short8 af[4], bfr[4];
#pragma unroll
        for (int i = 0; i < 4; ++i) af[i] = *(const short8*)(ap + i * 512);
#pragma unroll
        for (int j = 0; j < 4; ++j) bfr[j] = *(const short8*)(bp + j * 512);
#pragma unroll
        for (int i = 0; i < 4; ++i)
#pragma unroll
            for (int j = 0; j < 4; ++j)
                acc[i][j] = __builtin_amdgcn_mfma_f32_16x16x32_bf16(af[i], bfr[j], acc[i][j], 0, 0, 0);
    }
#pragma unroll
    for (int j = 0; j < 4; ++j) {
        int col = wc * 64 + j * 16 + cl;
        float bv = bias[col];
#pragma unroll
        for (int i = 0; i < 4; ++i) {
            int rbase = wr * 64 + i * 16 + q * 4;
#pragma unroll
            for (int r = 0; r < 4; ++r) {
                size_t o = (size_t)(row0 + rbase + r) * HH + col;
                eig[o] += acc[i][j][r] + bv;
            }
        }
    }
}

// ---------------- K8: LN2 + FFN1 + gelu + FFN2 + residual (MFMA, fused) ----------------
__global__ __launch_bounds__(256) void k_enc_ffn(float* __restrict__ eig, const float* __restrict__ g,
                                                 const float* __restrict__ be, const ushort* __restrict__ Wb,
                                                 const float* __restrict__ b1, const float* __restrict__ b2) {
    __shared__ ushort As[16384];
    __shared__ ushort Bs[16384];
    int row0 = blockIdx.x * 128;
    int t = threadIdx.x, lane = t & 63, w = t >> 6;
    int wr = w >> 1, wc = w & 1;
    {
        int r = t >> 1, half = t & 1;
        const float4* rowp = (const float4*)(eig + (size_t)(row0 + r) * HH + half * 64);
        float4 v[16];
        float s = 0.f, s2 = 0.f;
#pragma unroll
        for (int i = 0; i < 16; ++i) {
            float4 a = rowp[i]; v[i] = a;
            s += a.x + a.y + a.z + a.w;
            s2 += a.x * a.x + a.y * a.y + a.z * a.z + a.w * a.w;
        }
        s += __shfl_xor(s, 1); s2 += __shfl_xor(s2, 1);
        float mean = s * 0.0078125f;
        float var = s2 * 0.0078125f - mean * mean;
        float rstd = rsqrtf(var + 1e-5f);
        const float4* g4 = (const float4*)(g + half * 64);
        const float4* b4 = (const float4*)(be + half * 64);
#pragma unroll
        for (int ch = 0; ch < 8; ++ch) {
            float4 a = v[2 * ch], bq = v[2 * ch + 1];
            float4 ga = g4[2 * ch], gb = g4[2 * ch + 1];
            float4 ba = b4[2 * ch], bb = b4[2 * ch + 1];
            short8 u;
            u[0] = (short)f2bf((a.x - mean) * rstd * ga.x + ba.x);
            u[1] = (short)f2bf((a.y - mean) * rstd * ga.y + ba.y);
            u[2] = (short)f2bf((a.z - mean) * rstd * ga.z + ba.z);
            u[3] = (short)f2bf((a.w - mean) * rstd * ga.w + ba.w);
            u[4] = (short)f2bf((bq.x - mean) * rstd * gb.x + bb.x);
            u[5] = (short)f2bf((bq.y - mean) * rstd * gb.y + bb.y);
            u[6] = (short)f2bf((bq.z - mean) * rstd * gb.z + bb.z);
            u[7] = (short)f2bf((bq.w - mean) * rstd * gb.w + bb.w);
            int k = half * 64 + ch * 8;
            *(short8*)(As + (k >> 5) * 4096 + r * 32 + (k & 31)) = u;
        }
    }
#pragma unroll
    for (int p = 0; p < 8; ++p) {
        int ci = w * 8 + p;
        GLDS(Wb + WOFF_F1 + ci * 512 + lane * 8, Bs + ci * 512);
    }
    __syncthreads();
    int cl = lane & 15, q = lane >> 4;
    f32x4 acc[4][4] = {};
#pragma unroll
    for (int kt = 0; kt < 4; ++kt) {
        const ushort* ap = As + kt * 4096 + (wr * 64 + cl) * 32 + q * 8;
        const ushort* bp = Bs + kt * 4096 + (wc * 64 + cl) * 32 + q * 8;
        short8 af[4], bfr[4];
#pragma unroll
        for (int i = 0; i < 4; ++i) af[i] = *(const short8*)(ap + i * 512);
#pragma unroll
        for (int j = 0; j < 4; ++j) bfr[j] = *(const short8*)(bp + j * 512);
#pragma unroll
        for (int i = 0; i < 4; ++i)
#pragma unroll
            for (int j = 0; j < 4; ++j)
                acc[i][j] = __builtin_amdgcn_mfma_f32_16x16x32_bf16(af[i], bfr[j], acc[i][j], 0, 0, 0);
    }
    __syncthreads();   // all waves done reading As/Bs
    // h = gelu(acc + b1) -> As (bf16, chunked); restage Bs = W2
#pragma unroll
    for (int j = 0; j < 4; ++j) {
        int col = wc * 64 + j * 16 + cl;
        float bv = b1[col];
        int koff = (col >> 5) * 4096 + (col & 31);
#pragma unroll
        for (int i = 0; i < 4; ++i) {
            int rbase = wr * 64 + i * 16 + q * 4;
#pragma unroll
            for (int r = 0; r < 4; ++r) {
                float a = acc[i][j][r] + bv;
                float ge = 0.5f * a * (1.0f + erff(a * 0.7071067811865475f));
                As[koff + (rbase + r) * 32] = f2bf(ge);
            }
        }
    }
#pragma unroll
    for (int p = 0; p < 8; ++p) {
        int ci = w * 8 + p;
        GLDS(Wb + WOFF_F2 + ci * 512 + lane * 8, Bs + ci * 512);
    }
    __syncthreads();
    f32x4 acc2[4][4] = {};
#pragma unroll
    for (int kt = 0; kt < 4; ++kt) {
        const ushort* ap = As + kt * 4096 + (wr * 64 + cl) * 32 + q * 8;
        const ushort* bp = Bs + kt * 4096 + (wc * 64 + cl) * 32 + q * 8;
        short8 af[4], bfr[4];
#pragma unroll
        for (int i = 0; i < 4; ++i) af[i] = *(const short8*)(ap + i * 512);
#pragma unroll
        for (int j = 0; j < 4; ++j) bfr[j] = *(const short8*)(bp + j * 512);
#pragma unroll
        for (int i = 0; i < 4; ++i)
#pragma unroll
            for (int j = 0; j < 4; ++j)
                acc2[i][j] = __builtin_amdgcn_mfma_f32_16x16x32_bf16(af[i], bfr[j], acc2[i][j], 0, 0, 0);
    }
#pragma unroll
    for (int j = 0; j < 4; ++j) {
        int col = wc * 64 + j * 16 + cl;
        float bv = b2[col];
#pragma unroll
        for (int i = 0; i < 4; ++i) {
            int rbase = wr * 64 + i * 16 + q * 4;
#pragma unroll
            for (int r = 0; r < 4; ++r) {
                size_t o = (size_t)(row0 + rbase + r) * HH + col;
                eig[o] += acc2[i][j][r] + bv;
            }
        }
    }
}

// ---------------- K9: mean pool over N ----------------
__global__ __launch_bounds__(1024) void k_meanpool(const float* __restrict__ eig, float* __restrict__ me) {
    __shared__ float part[8][HH];
    int b = blockIdx.x, t = threadIdx.x;
    int col = t & 127, grp = t >> 7;
    const float* p = eig + (size_t)b * NV * HH + (size_t)grp * 128 * HH + col;
    float s = 0.f;
    for (int n = 0; n < 128; ++n) s += p[(size_t)n * HH];
    part[grp][col] = s;
    __syncthreads();
    if (t < 128) {
        float a = 0.f;
#pragma unroll
        for (int g2 = 0; g2 < 8; ++g2) a += part[g2][t];
        me[b * HH + t] = a * (1.0f / NV);
    }
}

// ---------------- K10: decoders ----------------
__global__ void k_decoders(const float* __restrict__ me,
                           const float* __restrict__ dscW, const float* __restrict__ dscb,
                           const float* __restrict__ dwavW, const float* __restrict__ dwavb,
                           const float* __restrict__ dsclW, const float* __restrict__ dsclb,
                           float* __restrict__ cs, float* __restrict__ cw, float* __restrict__ csc) {
    __shared__ float m[HH];
    __shared__ float s1[NCOE], s2[NCOE];
    __shared__ float sums[2];
    int b = blockIdx.x, t = threadIdx.x;
    m[t] = me[b * HH + t];
    m[t + 64] = me[b * HH + t + 64];
    __syncthreads();
    if (t < NCOE) {
        float a = dscb[t], a2 = dwavb[t];
        const float* w1 = dscW + t * HH;
        const float* w2 = dwavW + t * HH;
        for (int j = 0; j < HH; ++j) { a += m[j] * w1[j]; a2 += m[j] * w2[j]; }
        s1[t] = 1.f / (1.f + __expf(-a));
        s2[t] = 1.f / (1.f + __expf(-a2));
    }
    if (t < NSC) {
        float a = dsclb[t];
        const float* wv = dsclW + t * HH;
        for (int j = 0; j < HH; ++j) a += m[j] * wv[j];
        csc[b * NSC + t] = 5.0f / (1.f + __expf(-a));
    }
    __syncthreads();
    if (t == 0) {
        float a = 0.f, bb = 0.f;
        for (int c = 0; c < NCOE; ++c) { a += s1[c]; bb += s2[c]; }
        sums[0] = a; sums[1] = bb;
    }
    __syncthreads();
    if (t < NCOE) {
        cs[b * NCOE + t] = s1[t] / (sums[0] + 1e-8f);
        cw[b * NCOE + t] = s2[t] / (sums[1] + 1e-8f);
    }
}

// ---------------- K11: Chebyshev -> fsaT [B,5,N] normalized ----------------
__global__ void k_fsa(const float* __restrict__ ev, const float* __restrict__ cs,
                      const float* __restrict__ cw, const float* __restrict__ csc,
                      float* __restrict__ fsaT) {
    __shared__ float lcs[NCOE], lcw[NCOE], lsc[NSC];
    int gid = blockIdx.x * 256 + threadIdx.x;
    int b = gid >> 10, n = gid & (NV - 1);
    int t = threadIdx.x;
    if (t < NCOE) { lcs[t] = cs[b * NCOE + t]; lcw[t] = cw[b * NCOE + t]; }
    if (t < NSC) lsc[t] = csc[b * NSC + t];
    __syncthreads();
    float e = ev[gid];
    float x = e - 1.0f;
    float te = 1.f, to = x;
    float a0 = lcs[0] * 0.5f * (1.f - to);
    for (int c = 1; c < NCOE; ++c) {
        te = 2.f * x * to - te;
        to = 2.f * x * te - to;
        a0 += lcs[c] * 0.5f * (1.f - to);
    }
    float aw[NSC];
#pragma unroll
    for (int s = 0; s < NSC; ++s) {
        float f = e * lsc[s];
        if (f > 2.0f) f = 0.0f;
        float y = f - 1.0f;
        float te2 = 1.f, to2 = y, a = 0.f;
        for (int c = 1; c < NCOE; ++c) {
            te2 = 2.f * y * to2 - te2;
            to2 = 2.f * y * te2 - to2;
            a += lcw[c] * 0.5f * (1.f - te2);
        }
        aw[s] = a;
    }
    float n2 = a0 * a0;
#pragma unroll
    for (int s = 0; s < NSC; ++s) n2 += aw[s] * aw[s];
    float inv = 1.f / (sqrtf(n2) + 1e-8f);
    fsaT[((size_t)b * 5 + 0) * NV + n] = a0 * inv;
#pragma unroll
    for (int s = 0; s < NSC; ++s) fsaT[((size_t)b * 5 + 1 + s) * NV + n] = aw[s] * inv;
}

// ---------------- K12: eigenvector f32 -> bf16 ----------------
__global__ void k_tobf16(const float* __restrict__ in, ushort* __restrict__ outp) {
    int i = blockIdx.x * 256 + threadIdx.x;
    const float4* p = (const float4*)in + (size_t)i * 2;
    float4 a = p[0], bq = p[1];
    uint4 r;
    r.x = (uint)f2bf(a.x) | ((uint)f2bf(a.y) << 16);
    r.y = (uint)f2bf(a.z) | ((uint)f2bf(a.w) << 16);
    r.z = (uint)f2bf(bq.x) | ((uint)f2bf(bq.y) << 16);
    r.w = (uint)f2bf(bq.z) | ((uint)f2bf(bq.w) << 16);
    ((uint4*)outp)[i] = r;
}

// ---------------- K13: filters GEMM ----------------
__global__ __launch_bounds__(256) void k_gemm(const ushort* __restrict__ Vb,
                                              const float* __restrict__ fsaT,
                                              float* __restrict__ out,
                                              float* __restrict__ cn) {
    __shared__ ushort As[128 * 32];
    __shared__ ushort Bs[128 * 32];
    int tile = blockIdx.x;
    int bsid = blockIdx.y;
    int b = bsid / 5, s = bsid % 5;
    int n0 = (tile >> 3) * 128, m0 = (tile & 7) * 128;
    int tid = threadIdx.x, lane = tid & 63, w = tid >> 6;
    int wr = w >> 1, wc = w & 1;
    const ushort* Vbase = Vb + (size_t)b * NV * NV;
    const float* fs = fsaT + ((size_t)b * 5 + s) * NV;
    f32x4 acc[4][4] = {};

    for (int kt = 0; kt < NV / 32; ++kt) {
        int k0 = kt * 32;
        __syncthreads();
#pragma unroll
        for (int p = 0; p < 2; ++p) {
            int ci = w * 2 + p;
            int rrow = ci * 16 + (lane >> 2);
            int kch = (lane & 3) * 8;
            const ushort* gp = Vbase + (size_t)(m0 + rrow) * NV + k0 + kch;
            GLDS(gp, Bs + ci * 512);
        }
#pragma unroll
        for (int p = 0; p < 2; ++p) {
            int idx = p * 256 + tid;
            int rrow = idx >> 2;
            int kch = (idx & 3) * 8;
            const ushort* gp = Vbase + (size_t)(n0 + rrow) * NV + k0 + kch;
            uint4 raw = *(const uint4*)gp;
            const float4* fp = (const float4*)(fs + k0 + kch);
            float4 f0 = fp[0], f1 = fp[1];
            float v0 = __uint_as_float(raw.x << 16) * f0.x;
            float v1 = __uint_as_float(raw.x & 0xffff0000u) * f0.y;
            float v2 = __uint_as_float(raw.y << 16) * f0.z;
            float v3 = __uint_as_float(raw.y & 0xffff0000u) * f0.w;
            float v4 = __uint_as_float(raw.z << 16) * f1.x;
            float v5 = __uint_as_float(raw.z & 0xffff0000u) * f1.y;
            float v6 = __uint_as_float(raw.w << 16) * f1.z;
            float v7 = __uint_as_float(raw.w & 0xffff0000u) * f1.w;
            uint4 rr;
            rr.x = (uint)f2bf(v0) | ((uint)f2bf(v1) << 16);
            rr.y = (uint)f2bf(v2) | ((uint)f2bf(v3) << 16);
            rr.z = (uint)f2bf(v4) | ((uint)f2bf(v5) << 16);
            rr.w = (uint)f2bf(v6) | ((uint)f2bf(v7) << 16);
            *(uint4*)(As + rrow * 32 + kch) = rr;
        }
        __syncthreads();
        int cl = lane & 15, q = lane >> 4;
        const ushort* ap = As + ((wr * 64 + cl) * 32 + q * 8);
        const ushort* bp = Bs + ((wc * 64 + cl) * 32 + q * 8);
        short8 af[4], bfr[4];
#pragma unroll
        for (int i = 0; i < 4; ++i) af[i] = *(const short8*)(ap + i * 512);
#pragma unroll
        for (int j = 0; j < 4; ++j) bfr[j] = *(const short8*)(bp + j * 512);
#pragma unroll
        for (int i = 0; i < 4; ++i)
#pragma unroll
            for (int j = 0; j < 4; ++j)
                acc[i][j] = __builtin_amdgcn_mfma_f32_16x16x32_bf16(af[i], bfr[j], acc[i][j], 0, 0, 0);
    }
    int cl = lane & 15, q = lane >> 4;
    size_t ob = (size_t)(s * BB + b) * NV * NV;
    float colss[4] = {0.f, 0.f, 0.f, 0.f};
#pragma unroll
    for (int i = 0; i < 4; ++i) {
        int rbase = n0 + wr * 64 + i * 16 + q * 4;
#pragma unroll
        for (int j = 0; j < 4; ++j) {
            int col = m0 + wc * 64 + j * 16 + cl;
#pragma unroll
            for (int r = 0; r < 4; ++r) {
                float v = acc[i][j][r];
                out[ob + (size_t)(rbase + r) * NV + col] = v;
                colss[j] += v * v;
            }
        }
    }
    float* cnb = cn + (size_t)(s * BB + b) * NV;
#pragma unroll
    for (int j = 0; j < 4; ++j) {
        float v = colss[j];
        v += __shfl_xor(v, 16);
        v += __shfl_xor(v, 32);
        if (q == 0) atomicAdd(cnb + (m0 + wc * 64 + j * 16 + cl), v);
    }
}

// ---------------- K14: column normalization ----------------
__global__ void k_norm(float* __restrict__ out, const float* __restrict__ cn) {
    int bid = blockIdx.x;
    int bs = bid >> 10, n = bid & (NV - 1);
    int m4 = threadIdx.x * 4;
    float4 ssv = *(const float4*)(cn + (size_t)bs * NV + m4);
    float4* p = (float4*)(out + ((size_t)bs * NV + n) * NV + m4);
    float4 v = *p;
    v.x *= 1.f / fmaxf(sqrtf(ssv.x), 1e-12f);
    v.y *= 1.f / fmaxf(sqrtf(ssv.y), 1e-12f);
    v.z *= 1.f / fmaxf(sqrtf(ssv.z), 1e-12f);
    v.w *= 1.f / fmaxf(sqrtf(ssv.w), 1e-12f);
    *p = v;
}

extern "C" void kernel_launch(void* const* d_in, const int* in_sizes, int n_in,
                              void* d_out, int out_size, void* d_ws, size_t ws_size,
                              hipStream_t stream) {
    const float* eigenvalue = (const float*)d_in[0];
    const float* eigenvector = (const float*)d_in[1];
    const float* eigw_W = (const float*)d_in[2];
    const float* eigw_b = (const float*)d_in[3];
    const float* ln1_g = (const float*)d_in[4];
    const float* ln1_b = (const float*)d_in[5];
    const float* qkv_W = (const float*)d_in[6];
    const float* qkv_b = (const float*)d_in[7];
    const float* out_W = (const float*)d_in[8];
    const float* out_b = (const float*)d_in[9];
    const float* ln2_g = (const float*)d_in[10];
    const float* ln2_b = (const float*)d_in[11];
    const float* ffn1_W = (const float*)d_in[12];
    const float* ffn1_b = (const float*)d_in[13];
    const float* ffn2_W = (const float*)d_in[14];
    const float* ffn2_b = (const float*)d_in[15];
    const float* dsc_W = (const float*)d_in[16];
    const float* dsc_b = (const float*)d_in[17];
    const float* dwav_W = (const float*)d_in[18];
    const float* dwav_b = (const float*)d_in[19];
    const float* dscl_W = (const float*)d_in[20];
    const float* dscl_b = (const float*)d_in[21];

    char* w = (char*)d_ws;
    float* eig  = (float*)(w + 0);             // 4 MB
    float* me   = (float*)(w + 4194304);       // 4 KB
    float* cs   = (float*)(w + 4198400);       // 2 KB
    float* cw   = (float*)(w + 4200448);       // 2 KB
    float* csc  = (float*)(w + 4202496);       // 1 KB
    float* fsaT = (float*)(w + 4203520);       // 160 KB
    float* cn   = (float*)(w + 4367360);       // 160 KB
    ushort* qb  = (ushort*)(w + 4531200);      // 2 MB
    ushort* kb  = (ushort*)(w + 6628352);      // 2 MB
    ushort* vb  = (ushort*)(w + 8725504);      // 2 MB
    ushort* vt  = (ushort*)(w + 10822656);     // 2 MB
    ushort* obuf = (ushort*)(w + 12919808);    // 2 MB
    ushort* Wb  = (ushort*)(w + 15016960);     // 224 KB
    ushort* Vb  = (ushort*)(w + 15246336);     // 16 MB -> end 32,023,552

    float* outp = (float*)d_out;
    float* S = (float*)d_out;   // scratch region, overwritten later by k_gemm

    hipMemsetAsync(cn, 0, 40 * NV * sizeof(float), stream);

    k_wcvt<<<dim3(WB_ELEMS / 256), dim3(256), 0, stream>>>(eigw_W, qkv_W, out_W, ffn1_W, ffn2_W, Wb);
    k_enc_sine<<<dim3(64), dim3(256), 0, stream>>>(eigenvalue, Wb, eigw_W, eigw_b, eig);
    k_enc_qkv<<<dim3(64), dim3(256), 0, stream>>>(eig, ln1_g, ln1_b, Wb, qkv_b, qb, kb, vb);
    k_vt<<<dim3(4, 32), dim3(256), 0, stream>>>(vb, vt);
    k_qk<<<dim3(64, 32), dim3(256), 0, stream>>>(qb, kb, S);
    k_softmax<<<dim3(32 * NV), dim3(256), 0, stream>>>(S);
    k_pv<<<dim3(8, 32), dim3(256), 0, stream>>>(S, vt, obuf);
    k_enc_proj<<<dim3(64), dim3(256), 0, stream>>>(obuf, Wb, out_b, eig);
    k_enc_ffn<<<dim3(64), dim3(256), 0, stream>>>(eig, ln2_g, ln2_b, Wb, ffn1_b, ffn2_b);
    k_meanpool<<<dim3(BB), dim3(1024), 0, stream>>>(eig, me);
    k_decoders<<<dim3(BB), dim3(64), 0, stream>>>(me, dsc_W, dsc_b, dwav_W, dwav_b, dscl_W, dscl_b, cs, cw, csc);
    k_fsa<<<dim3(BB * NV / 256), dim3(256), 0, stream>>>(eigenvalue, cs, cw, csc, fsaT);
    k_tobf16<<<dim3(BB * NV * NV / (8 * 256)), dim3(256), 0, stream>>>(eigenvector, Vb);
    k_gemm<<<dim3(64, 40), dim3(256), 0, stream>>>(Vb, fsaT, outp, cn);
    k_norm<<<dim3(40 * NV), dim3(256), 0, stream>>>(outp, cn);
}